// Round 1
// 93.435 us; speedup vs baseline: 1.1913x; 1.1913x over previous
//
#include <hip/hip_runtime.h>

// SpectralConv2d: B=2,L=8,C=64,H=64,W=33, M1=M2=16
// Round 1: latency-bound fix.
//  - 512 compute blocks: corner(2) x xrow(16) x oq(4) x blq(4); 256 thr.
//  - thread = (yq 0..3 [4y via float4], blj 0..3 [bl], ol 0..15 [o]).
//  - x corner slice staged in LDS once (32KB, [r][c][blj][y16]) via
//    coalesced scalar loads; c-loop reads it as conflict-free ds_read_b128.
//  - weights read as ALIGNED float4 (offsets multiple of 16B), amortized
//    over 4 bl per block (L2 re-fetch 16x -> 4x).
//  - inner loop per c: 2 global dwordx4 + 2 ds_read_b128 + 16 FMA.
//  - zero-fill: same proven coverage as previous kernel (row tails in
//    compute blocks, middle rows h in [16,48) in 2048 fill blocks).

constexpr int Cc    = 64;
constexpr int Ww    = 33;
constexpr int HW    = 64 * Ww;        // 2112
constexpr int PLANE = Cc * HW;        // 135168
constexpr int TOT   = 16 * PLANE;     // 2162688 (elements in real half)
constexpr int WSTR  = Cc * 16 * 16;   // 16384: o-stride in weight tensor

__global__ __launch_bounds__(256) void spectral_fused_kernel(
    const float* __restrict__ xr, const float* __restrict__ xi,
    const float* __restrict__ wr1, const float* __restrict__ wi1,
    const float* __restrict__ wr2, const float* __restrict__ wi2,
    float* __restrict__ out)
{
    const int bid = blockIdx.x;
    const int t   = threadIdx.x;

    if (bid < 512) {
        // ---- compute blocks: oq(4) | blq(4) | xrow(16) | corner(2) ----
        const int oq     = bid & 3;
        const int blq    = (bid >> 2) & 3;
        const int xrow   = (bid >> 4) & 15;
        const int corner = bid >> 8;
        const int xin    = corner ? (48 + xrow) : xrow;
        const float* wr  = corner ? wr2 : wr1;
        const float* wi  = corner ? wi2 : wi1;

        // [r(2)][c(64)][blj(4)][y(16)] floats = 8192 floats = 32 KB
        __shared__ __align__(16) float xs[8192];

        // ---- stage x slice: coalesced scalar loads, 2-way-max ds_write banks
        {
            const int y  = t & 15;          // 16 consecutive floats per row
            const int wb = (t >> 4) & 3;    // bl within block
            const int cg = t >> 6;          // wave id -> c low bits (uniform/wave)
            const int src_base = (blq * 4 + wb) * PLANE + xin * Ww + y;
            #pragma unroll
            for (int k = 0; k < 32; ++k) {
                const int r = k >> 4;                 // 0: real, 1: imag
                const int c = ((k & 15) << 2) | cg;   // covers 0..63
                const float* src = (r ? xi : xr) + (size_t)src_base + c * HW;
                xs[r * 4096 + c * 64 + wb * 16 + y] = *src;
            }
        }
        __syncthreads();

        // ---- compute: thread = (yq, blj, ol) ----
        const int yq  = t & 3;
        const int blj = (t >> 2) & 3;
        const int ol  = t >> 4;
        const int o   = oq * 16 + ol;
        const int bl  = blq * 4 + blj;

        const float* wrp = wr + o * WSTR + xrow * 16 + yq * 4;  // + c*256 (16B-aligned)
        const float* wip = wi + o * WSTR + xrow * 16 + yq * 4;
        const float4* xsr = reinterpret_cast<const float4*>(xs) + blj * 4 + yq; // + c*16
        const float4* xsi = xsr + 1024;                                         // imag half

        float4 ar = make_float4(0.f, 0.f, 0.f, 0.f);
        float4 ai = make_float4(0.f, 0.f, 0.f, 0.f);

        #pragma unroll 8
        for (int c = 0; c < Cc; ++c) {
            const float4 wre = *reinterpret_cast<const float4*>(wrp + c * 256);
            const float4 wim = *reinterpret_cast<const float4*>(wip + c * 256);
            const float4 a   = xsr[c * 16];
            const float4 b   = xsi[c * 16];
            ar.x = fmaf(a.x, wre.x, ar.x); ar.x = fmaf(-b.x, wim.x, ar.x);
            ai.x = fmaf(a.x, wim.x, ai.x); ai.x = fmaf( b.x, wre.x, ai.x);
            ar.y = fmaf(a.y, wre.y, ar.y); ar.y = fmaf(-b.y, wim.y, ar.y);
            ai.y = fmaf(a.y, wim.y, ai.y); ai.y = fmaf( b.y, wre.y, ai.y);
            ar.z = fmaf(a.z, wre.z, ar.z); ar.z = fmaf(-b.z, wim.z, ar.z);
            ai.z = fmaf(a.z, wim.z, ai.z); ai.z = fmaf( b.z, wre.z, ai.z);
            ar.w = fmaf(a.w, wre.w, ar.w); ar.w = fmaf(-b.w, wim.w, ar.w);
            ai.w = fmaf(a.w, wim.w, ai.w); ai.w = fmaf( b.w, wre.w, ai.w);
        }

        const size_t ob = (size_t)(bl * Cc + o) * HW + xin * Ww + yq * 4;
        out[ob + 0] = ar.x; out[ob + 1] = ar.y;
        out[ob + 2] = ar.z; out[ob + 3] = ar.w;
        out[TOT + ob + 0] = ai.x; out[TOT + ob + 1] = ai.y;
        out[TOT + ob + 2] = ai.z; out[TOT + ob + 3] = ai.w;

        // ---- zero y in [16,33) tails of this block's rows (16 o x 4 bl x 2 ri)
        // 2176 = 2 * 16 * 4 * 17 elements; k = t, t+256, ..., t+2048.
        #pragma unroll
        for (int q = 0; q < 9; ++q) {
            const int k = t + q * 256;
            if (k < 2176) {
                const int ri   = k >= 1088;
                const int rem  = ri ? (k - 1088) : k;
                const int ol_  = rem / 68;            // local o (0..15)
                const int sub  = rem - ol_ * 68;      // 68 = 4 bl * 17 y
                const int blj_ = sub / 17;
                const int yy   = 16 + (sub - blj_ * 17);
                const size_t idx = (size_t)((blq * 4 + blj_) * Cc + oq * 16 + ol_) * HW
                                 + (size_t)xin * Ww + yy + (ri ? (size_t)TOT : 0);
                out[idx] = 0.f;
            }
        }
    } else {
        // ---- zero blocks: one per (ri, bl, o) plane, middle rows h in [16,48)
        // 1056 contiguous floats at plane*2112 + 528 -> 264 float4.
        const int p     = bid - 512;          // [0, 2048)
        const int ri    = p >> 10;
        const int plane = p & 1023;           // bl*64 + o
        float4* dst = (float4*)(out + (size_t)ri * TOT + (size_t)plane * HW + 528);
        const float4 z = make_float4(0.f, 0.f, 0.f, 0.f);
        dst[t] = z;
        if (t < 8) dst[256 + t] = z;          // 264 = 256 + 8
    }
}

extern "C" void kernel_launch(void* const* d_in, const int* in_sizes, int n_in,
                              void* d_out, int out_size, void* d_ws, size_t ws_size,
                              hipStream_t stream) {
    const float* xr  = (const float*)d_in[0];
    const float* xi  = (const float*)d_in[1];
    const float* wr1 = (const float*)d_in[2];
    const float* wi1 = (const float*)d_in[3];
    const float* wr2 = (const float*)d_in[4];
    const float* wi2 = (const float*)d_in[5];
    float* out = (float*)d_out;

    spectral_fused_kernel<<<2560, 256, 0, stream>>>(xr, xi, wr1, wi1, wr2, wi2, out);
}